// Round 1
// baseline (3969.007 us; speedup 1.0000x reference)
//
#include <hip/hip_runtime.h>

#define UNITS 32
#define TSTEPS 48
#define OUT_STEPS 24

// sigmoid(x) = 1 / (1 + exp(-x)) = 1 / (1 + 2^(-x*log2e))
__device__ __forceinline__ float fast_sigmoid(float x) {
    float e = __builtin_amdgcn_exp2f(x * -1.44269504088896340736f);
    return __builtin_amdgcn_rcpf(1.0f + e);
}

// tanh(x) = sign(x) * (1 - 2/(1 + exp(2|x|)))  -- overflow-safe: exp arg >= 0,
// exp2 -> inf gives rcp(inf)=0 -> t=1 (correct saturation), no NaN.
__device__ __forceinline__ float fast_tanh(float x) {
    float ax = __builtin_fabsf(x);
    float e = __builtin_amdgcn_exp2f(ax * 2.88539008177792681472f); // exp(2|x|)
    float t = 1.0f - 2.0f * __builtin_amdgcn_rcpf(1.0f + e);
    return __builtin_copysignf(t, x);
}

// One Keras LSTMCell step. Weights are wave-uniform (same for all lanes) with
// compile-time offsets -> compiler emits scalar loads (s_load) and folds them
// as SGPR operands into v_fmac_f32. h/c/hn fully unrolled -> stay in VGPRs.
__device__ __forceinline__ void lstm_cell(float x, float (&h)[UNITS], float (&c)[UNITS],
                                          const float* __restrict__ Wk,
                                          const float* __restrict__ Uk,
                                          const float* __restrict__ bv) {
    float hn[UNITS];
#pragma unroll
    for (int u = 0; u < UNITS; ++u) {
        float zi = bv[u]      + x * Wk[u];
        float zf = bv[u + 32] + x * Wk[u + 32];
        float zg = bv[u + 64] + x * Wk[u + 64];
        float zo = bv[u + 96] + x * Wk[u + 96];
#pragma unroll
        for (int k = 0; k < UNITS; ++k) {
            const float hk = h[k];
            zi += hk * Uk[k * 128 + u];
            zf += hk * Uk[k * 128 + u + 32];
            zg += hk * Uk[k * 128 + u + 64];
            zo += hk * Uk[k * 128 + u + 96];
        }
        float ig = fast_sigmoid(zi);
        float fg = fast_sigmoid(zf);
        float gg = fast_tanh(zg);
        float og = fast_sigmoid(zo);
        float cn = fg * c[u] + ig * gg;
        c[u] = cn;
        hn[u] = og * fast_tanh(cn);
    }
#pragma unroll
    for (int u = 0; u < UNITS; ++u) h[u] = hn[u];
}

__global__ __launch_bounds__(256) void lstm_feedback_kernel(
    const float* __restrict__ inputs,  // [B, 48]
    const float* __restrict__ Wk_w,    // [1,128]
    const float* __restrict__ Uk_w,    // [32,128]
    const float* __restrict__ b_w,     // [128]
    const float* __restrict__ Wk_d,    // [1,128]
    const float* __restrict__ Uk_d,    // [32,128]
    const float* __restrict__ b_d,     // [128]
    const float* __restrict__ Wd,      // [32,1]
    const float* __restrict__ bd,      // [1]
    float* __restrict__ out,           // [B, 24]
    int B) {
    const int b = blockIdx.x * blockDim.x + threadIdx.x;
    if (b >= B) return;

    float h[UNITS], c[UNITS];
#pragma unroll
    for (int u = 0; u < UNITS; ++u) { h[u] = 0.0f; c[u] = 0.0f; }

    const float* __restrict__ inp = inputs + (long)b * TSTEPS;

    // Warmup over the 48-step input window (t-loop NOT unrolled: code size).
    for (int t = 0; t < TSTEPS; ++t) {
        const float x = inp[t];
        lstm_cell(x, h, c, Wk_w, Uk_w, b_w);
    }

    // Dense projection to first prediction.
    float pred = bd[0];
#pragma unroll
    for (int u = 0; u < UNITS; ++u) pred += h[u] * Wd[u];

    float* __restrict__ op = out + (long)b * OUT_STEPS;
    op[0] = pred;

    // Autoregressive decode: feed prediction back.
    for (int s = 1; s < OUT_STEPS; ++s) {
        lstm_cell(pred, h, c, Wk_d, Uk_d, b_d);
        pred = bd[0];
#pragma unroll
        for (int u = 0; u < UNITS; ++u) pred += h[u] * Wd[u];
        op[s] = pred;
    }
}

extern "C" void kernel_launch(void* const* d_in, const int* in_sizes, int n_in,
                              void* d_out, int out_size, void* d_ws, size_t ws_size,
                              hipStream_t stream) {
    const float* inputs = (const float*)d_in[0];
    const float* Wk_w   = (const float*)d_in[1];
    const float* Uk_w   = (const float*)d_in[2];
    const float* b_w    = (const float*)d_in[3];
    const float* Wk_d   = (const float*)d_in[4];
    const float* Uk_d   = (const float*)d_in[5];
    const float* b_d    = (const float*)d_in[6];
    const float* Wd     = (const float*)d_in[7];
    const float* bd     = (const float*)d_in[8];
    float* out = (float*)d_out;

    const int B = in_sizes[0] / TSTEPS;  // F == 1
    const int block = 256;
    const int grid = (B + block - 1) / block;
    lstm_feedback_kernel<<<grid, block, 0, stream>>>(
        inputs, Wk_w, Uk_w, b_w, Wk_d, Uk_d, b_d, Wd, bd, out, B);
}

// Round 2
// 531.232 us; speedup vs baseline: 7.4713x; 7.4713x over previous
//
#include <hip/hip_runtime.h>

#define UNITS 32
#define TSTEPS 48
#define OUT_STEPS 24

typedef __attribute__((ext_vector_type(8))) short bf16x8;
typedef __attribute__((ext_vector_type(4))) float f32x4;

// sigmoid(x) = 1/(1+2^(-x*log2e)); rcp/exp are HW approx (~1ulp), OK vs 1.8e-3 tol.
__device__ __forceinline__ float fast_sigmoid(float x) {
    float e = __builtin_amdgcn_exp2f(x * -1.44269504088896340736f);
    return __builtin_amdgcn_rcpf(1.0f + e);
}
// tanh(x) = sign(x)*(1 - 2/(1+exp(2|x|))) — overflow-safe (exp arg >= 0).
__device__ __forceinline__ float fast_tanh(float x) {
    float ax = __builtin_fabsf(x);
    float e = __builtin_amdgcn_exp2f(ax * 2.88539008177792681472f);
    float t = 1.0f - 2.0f * __builtin_amdgcn_rcpf(1.0f + e);
    return __builtin_copysignf(t, x);
}

// Split f32 -> bf16 hi (RNE) + bf16 lo (truncated residual). hi+lo ~ 17-bit mantissa.
__device__ __forceinline__ void bf_split(float f, short& hi, short& lo) {
    unsigned u = __builtin_bit_cast(unsigned, f);
    unsigned r = u + 0x7FFFu + ((u >> 16) & 1u);
    unsigned short hb = (unsigned short)(r >> 16);
    float hif = __builtin_bit_cast(float, (unsigned)hb << 16);
    float lof = f - hif;                       // exact (cancellation)
    unsigned short lb = (unsigned short)(__builtin_bit_cast(unsigned, lof) >> 16);
    hi = (short)hb; lo = (short)lb;
}

// Load B-fragments (hi/lo split) + per-lane col constants for one LSTM cell's weights.
// B-frag layout: lane holds B[k = (lane>>4)*8 + j][n = lane&15] for tile n-range [16t,16t+16).
__device__ __forceinline__ void load_bfrags(const float* __restrict__ Uk,
                                            const float* __restrict__ Wk,
                                            const float* __restrict__ bvec,
                                            bf16x8* Bhi, bf16x8* Blo,
                                            float* wkn, float* bn, int LQ, int LC) {
#pragma unroll
    for (int t = 0; t < 8; ++t) {
        const int n = 16 * t + LC;
        bf16x8 bh, bl;
#pragma unroll
        for (int j = 0; j < 8; ++j) {
            float w = Uk[(LQ * 8 + j) * 128 + n];
            short hb, lb; bf_split(w, hb, lb);
            bh[j] = hb; bl[j] = lb;
        }
        Bhi[t] = bh; Blo[t] = bl;
        wkn[t] = Wk[n];
        bn[t]  = bvec[n];
    }
}

// One LSTM step for 16 batch rows held by this wave.
// A-frags read from LDS (written by previous step); new h written back (hi/lo bf16).
// C/D layout: D[row=(lane>>4)*4+reg][col=lane&15]; tiles 0..7 cover gates i,i,f,f,g,g,o,o.
__device__ __forceinline__ void lstm_step(
    const short* __restrict__ ahi_s, const short* __restrict__ alo_s,
    short* __restrict__ ahi_w, short* __restrict__ alo_w,
    const bf16x8* Bhi, const bf16x8* Blo,
    const float* wkn, const float* bn,
    const float x[4], float c0[4], float c1[4], float h0[4], float h1[4],
    int LQ, int LC) {
    const bf16x8 va_hi = *(const bf16x8*)(ahi_s + LC * 32 + LQ * 8);
    const bf16x8 va_lo = *(const bf16x8*)(alo_s + LC * 32 + LQ * 8);

    f32x4 acc[8];
#pragma unroll
    for (int t = 0; t < 8; ++t) {
        f32x4 a = {0.f, 0.f, 0.f, 0.f};
        a = __builtin_amdgcn_mfma_f32_16x16x32_bf16(va_lo, Bhi[t], a, 0, 0, 0);
        a = __builtin_amdgcn_mfma_f32_16x16x32_bf16(va_hi, Blo[t], a, 0, 0, 0);
        a = __builtin_amdgcn_mfma_f32_16x16x32_bf16(va_hi, Bhi[t], a, 0, 0, 0);
        acc[t] = a;
    }

#pragma unroll
    for (int half = 0; half < 2; ++half) {
        float* cc = half ? c1 : c0;
        float* hh = half ? h1 : h0;
#pragma unroll
        for (int j = 0; j < 4; ++j) {
            float zi = acc[0 + half][j] + bn[0 + half] + x[j] * wkn[0 + half];
            float zf = acc[2 + half][j] + bn[2 + half] + x[j] * wkn[2 + half];
            float zg = acc[4 + half][j] + bn[4 + half] + x[j] * wkn[4 + half];
            float zo = acc[6 + half][j] + bn[6 + half] + x[j] * wkn[6 + half];
            float ig = fast_sigmoid(zi);
            float fg = fast_sigmoid(zf);
            float gg = fast_tanh(zg);
            float og = fast_sigmoid(zo);
            float cn = fg * cc[j] + ig * gg;
            cc[j] = cn;
            hh[j] = og * fast_tanh(cn);
        }
    }
    // Write new h (hi/lo) to LDS at [m = LQ*4+j][u = LC + 16*half] for next step's A-frag.
#pragma unroll
    for (int half = 0; half < 2; ++half) {
        const float* hh = half ? h1 : h0;
#pragma unroll
        for (int j = 0; j < 4; ++j) {
            const int idx = (LQ * 4 + j) * 32 + LC + 16 * half;
            short hb, lb; bf_split(hh[j], hb, lb);
            ahi_w[idx] = hb;
            alo_w[idx] = lb;
        }
    }
}

__global__ __launch_bounds__(64, 3) void lstm_feedback_mfma(
    const float* __restrict__ inputs,  // [B, 48]
    const float* __restrict__ Wk_w, const float* __restrict__ Uk_w, const float* __restrict__ b_w,
    const float* __restrict__ Wk_d, const float* __restrict__ Uk_d, const float* __restrict__ b_d,
    const float* __restrict__ Wd, const float* __restrict__ bd,
    float* __restrict__ out,           // [B, 24]
    int B) {
    const int lane = threadIdx.x;      // block = 64 = one wave
    const int LQ = lane >> 4;          // quad group 0..3
    const int LC = lane & 15;          // col within tile
    const int mbase = blockIdx.x * 16; // 16 batch rows per wave

    __shared__ __align__(16) short ahi_s[16 * 32];
    __shared__ __align__(16) short alo_s[16 * 32];
    __shared__ float xbuf[16 * 49];    // padded stride 49: conflict-free column reads
    __shared__ float predbuf[16 * 24];

    // Cooperative load of this wave's input block (coalesced), into padded LDS.
    for (int i = lane; i < 16 * 48; i += 64) {
        int m = i / 48, t = i - m * 48;
        xbuf[m * 49 + t] = inputs[(long)mbase * 48 + i];
    }
    // h = 0 staging
    for (int i = lane; i < 512; i += 64) { ahi_s[i] = 0; alo_s[i] = 0; }

    bf16x8 Bhi[8], Blo[8];
    float wkn[8], bn[8];
    load_bfrags(Uk_w, Wk_w, b_w, Bhi, Blo, wkn, bn, LQ, LC);

    float c0[4] = {0, 0, 0, 0}, c1[4] = {0, 0, 0, 0};
    float h0[4], h1[4], x[4];

    // ---- warmup over 48 input steps ----
    for (int t = 0; t < TSTEPS; ++t) {
        __syncthreads();
#pragma unroll
        for (int j = 0; j < 4; ++j) x[j] = xbuf[(LQ * 4 + j) * 49 + t];
        lstm_step(ahi_s, alo_s, ahi_s, alo_s, Bhi, Blo, wkn, bn, x, c0, c1, h0, h1, LQ, LC);
    }

    // ---- first prediction ----
    const float wd0 = Wd[LC], wd1 = Wd[LC + 16], bdv = bd[0];
    float pred[4];
#pragma unroll
    for (int j = 0; j < 4; ++j) pred[j] = h0[j] * wd0 + h1[j] * wd1;
#pragma unroll
    for (int mask = 1; mask < 16; mask <<= 1) {
#pragma unroll
        for (int j = 0; j < 4; ++j) pred[j] += __shfl_xor(pred[j], mask);
    }
#pragma unroll
    for (int j = 0; j < 4; ++j) pred[j] += bdv;
    if (LC == 0) {
#pragma unroll
        for (int j = 0; j < 4; ++j) predbuf[(LQ * 4 + j) * 24 + 0] = pred[j];
    }

    // ---- decode: swap in decode-cell weights ----
    load_bfrags(Uk_d, Wk_d, b_d, Bhi, Blo, wkn, bn, LQ, LC);

    for (int s = 1; s < OUT_STEPS; ++s) {
        __syncthreads();
#pragma unroll
        for (int j = 0; j < 4; ++j) x[j] = pred[j];
        lstm_step(ahi_s, alo_s, ahi_s, alo_s, Bhi, Blo, wkn, bn, x, c0, c1, h0, h1, LQ, LC);
#pragma unroll
        for (int j = 0; j < 4; ++j) pred[j] = h0[j] * wd0 + h1[j] * wd1;
#pragma unroll
        for (int mask = 1; mask < 16; mask <<= 1) {
#pragma unroll
            for (int j = 0; j < 4; ++j) pred[j] += __shfl_xor(pred[j], mask);
        }
#pragma unroll
        for (int j = 0; j < 4; ++j) pred[j] += bdv;
        if (LC == 0) {
#pragma unroll
            for (int j = 0; j < 4; ++j) predbuf[(LQ * 4 + j) * 24 + s] = pred[j];
        }
    }

    // ---- coalesced output flush ----
    __syncthreads();
    for (int i = lane; i < 16 * 24; i += 64) out[(long)mbase * 24 + i] = predbuf[i];
}

extern "C" void kernel_launch(void* const* d_in, const int* in_sizes, int n_in,
                              void* d_out, int out_size, void* d_ws, size_t ws_size,
                              hipStream_t stream) {
    const float* inputs = (const float*)d_in[0];
    const float* Wk_w   = (const float*)d_in[1];
    const float* Uk_w   = (const float*)d_in[2];
    const float* b_w    = (const float*)d_in[3];
    const float* Wk_d   = (const float*)d_in[4];
    const float* Uk_d   = (const float*)d_in[5];
    const float* b_d    = (const float*)d_in[6];
    const float* Wd     = (const float*)d_in[7];
    const float* bd     = (const float*)d_in[8];
    float* out = (float*)d_out;

    const int B = in_sizes[0] / TSTEPS;
    const int grid = (B + 15) / 16;   // one wave (64-thread block) per 16 batch rows
    lstm_feedback_mfma<<<grid, 64, 0, stream>>>(
        inputs, Wk_w, Uk_w, b_w, Wk_d, Uk_d, b_d, Wd, bd, out, B);
}

// Round 3
// 486.565 us; speedup vs baseline: 8.1572x; 1.0918x over previous
//
#include <hip/hip_runtime.h>

#define TSTEPS 48
#define OUT_STEPS 24

typedef __attribute__((ext_vector_type(8))) short bf16x8;
typedef __attribute__((ext_vector_type(4))) float f32x4;

// sigmoid(x) = 1/(1+2^(-x*log2e)); HW rcp/exp approx (~1ulp) OK vs 1.8e-3 tol.
__device__ __forceinline__ float fast_sigmoid(float x) {
    float e = __builtin_amdgcn_exp2f(x * -1.44269504088896340736f);
    return __builtin_amdgcn_rcpf(1.0f + e);
}
// tanh(x) = 2*sigmoid(2x)-1. Inf-safe both directions: exp2(+inf)->inf, rcp(inf)=0 -> -1;
// exp2(-inf)->0 -> rcp(1)=1 -> +1. No NaN paths.
__device__ __forceinline__ float fast_tanh(float x) {
    float e = __builtin_amdgcn_exp2f(x * -2.88539008177792681472f);
    float s = __builtin_amdgcn_rcpf(1.0f + e);
    return 2.0f * s - 1.0f;
}

// Split f32 -> bf16 hi (RNE) + bf16 lo (residual, truncated). hi+lo ~17-bit mantissa.
__device__ __forceinline__ void bf_split(float f, short& hi, short& lo) {
    unsigned u = __builtin_bit_cast(unsigned, f);
    unsigned r = u + 0x7FFFu + ((u >> 16) & 1u);
    unsigned short hb = (unsigned short)(r >> 16);
    float hif = __builtin_bit_cast(float, (unsigned)hb << 16);
    float lof = f - hif;  // exact
    unsigned short lb = (unsigned short)(__builtin_bit_cast(unsigned, lof) >> 16);
    hi = (short)hb; lo = (short)lb;
}

// Load A-fragments (U^T, permuted gate-unit rows, hi/lo split) + per-lane fp32
// Wk/b constants in D-layout order.
// Row permutation: row R=16t+rho  <->  gate=(t>>1), unit u=(rho>>2)*8+(t&1)*4+(rho&3).
// A-frag: lane(LQ,LC) elem j = A[m=16t+LC][k=LQ*8+j] = Uk[(LQ*8+j)*128 + origcol].
__device__ __forceinline__ void load_weights(const float* __restrict__ Uk,
                                             const float* __restrict__ Wk,
                                             const float* __restrict__ bv,
                                             bf16x8* Ahi, bf16x8* Alo,
                                             f32x4* wkfr, f32x4* bfr, int LQ, int LC) {
    const int ulo = ((LC >> 2) << 3) + (LC & 3);
#pragma unroll
    for (int t = 0; t < 8; ++t) {
        const int col = (t >> 1) * 32 + ulo + (t & 1) * 4;  // orig column for A row 16t+LC
        bf16x8 ah, al;
#pragma unroll
        for (int j = 0; j < 8; ++j) {
            float w = Uk[(LQ * 8 + j) * 128 + col];
            short hb, lb; bf_split(w, hb, lb);
            ah[j] = hb; al[j] = lb;
        }
        Ahi[t] = ah; Alo[t] = al;
        const int colb = (t >> 1) * 32 + LQ * 8 + (t & 1) * 4;  // orig col for D row 16t+LQ*4+r
#pragma unroll
        for (int r = 0; r < 4; ++r) {
            wkfr[t][r] = Wk[colb + r];
            bfr[t][r]  = bv[colb + r];
        }
    }
}

// One step. h fragments are ALREADY in B-frag layout; new h exits in B-frag layout
// (identity transform under the weight permutation). No LDS, no barriers.
__device__ __forceinline__ void lstm_step2(float x,
    const bf16x8* Ahi, const bf16x8* Alo,
    const f32x4* wkfr, const f32x4* bfr,
    bf16x8& h_hi, bf16x8& h_lo, float* c, float* hv) {
    f32x4 acc[8];
#pragma unroll
    for (int t = 0; t < 8; ++t) {
        f32x4 a;
#pragma unroll
        for (int r = 0; r < 4; ++r) a[r] = __builtin_fmaf(x, wkfr[t][r], bfr[t][r]);
        a = __builtin_amdgcn_mfma_f32_16x16x32_bf16(Alo[t], h_hi, a, 0, 0, 0);
        a = __builtin_amdgcn_mfma_f32_16x16x32_bf16(Ahi[t], h_lo, a, 0, 0, 0);
        a = __builtin_amdgcn_mfma_f32_16x16x32_bf16(Ahi[t], h_hi, a, 0, 0, 0);
        acc[t] = a;
    }
    bf16x8 nh, nl;
#pragma unroll
    for (int tl = 0; tl < 2; ++tl) {
#pragma unroll
        for (int r = 0; r < 4; ++r) {
            const int j = tl * 4 + r;
            float ig = fast_sigmoid(acc[0 + tl][r]);
            float fg = fast_sigmoid(acc[2 + tl][r]);
            float gg = fast_tanh(acc[4 + tl][r]);
            float og = fast_sigmoid(acc[6 + tl][r]);
            float cn = fg * c[j] + ig * gg;
            c[j] = cn;
            float h = og * fast_tanh(cn);
            hv[j] = h;
            short hb, lb; bf_split(h, hb, lb);
            nh[j] = hb; nl[j] = lb;
        }
    }
    h_hi = nh; h_lo = nl;
}

__global__ __launch_bounds__(64, 2) void lstm_feedback_mfma2(
    const float* __restrict__ inputs,  // [B, 48]
    const float* __restrict__ Wk_w, const float* __restrict__ Uk_w, const float* __restrict__ b_w,
    const float* __restrict__ Wk_d, const float* __restrict__ Uk_d, const float* __restrict__ b_d,
    const float* __restrict__ Wd, const float* __restrict__ bd,
    float* __restrict__ out,           // [B, 24]
    int B) {
    const int lane = threadIdx.x;      // block = 64 = one wave
    const int LQ = lane >> 4;
    const int LC = lane & 15;          // this lane's batch column
    const int mbase = blockIdx.x * 16;

    __shared__ float xbuf[16 * 49];    // stride 49 -> conflict-free column reads
    __shared__ float predbuf[16 * 25]; // stride 25 -> conflict-free scattered writes

    // Coalesced cooperative load of the wave's 16x48 input block.
    for (int i = lane; i < 16 * TSTEPS; i += 64) {
        int m = i / TSTEPS, t = i - m * TSTEPS;
        xbuf[m * 49 + t] = inputs[(long)mbase * TSTEPS + i];
    }

    bf16x8 Ahi[8], Alo[8];
    f32x4 wkfr[8], bfr[8];
    load_weights(Uk_w, Wk_w, b_w, Ahi, Alo, wkfr, bfr, LQ, LC);

    bf16x8 h_hi = {0, 0, 0, 0, 0, 0, 0, 0};
    bf16x8 h_lo = {0, 0, 0, 0, 0, 0, 0, 0};
    float c[8] = {0, 0, 0, 0, 0, 0, 0, 0};
    float hv[8];

    float wdv[8];
#pragma unroll
    for (int j = 0; j < 8; ++j) wdv[j] = Wd[LQ * 8 + j];
    const float bdv = bd[0];

    __syncthreads();  // xbuf visible

    // ---- warmup: 48 steps, zero LDS/barriers inside ----
    for (int t = 0; t < TSTEPS; ++t) {
        float x = xbuf[LC * 49 + t];
        lstm_step2(x, Ahi, Alo, wkfr, bfr, h_hi, h_lo, c, hv);
    }

    // ---- first prediction: partial dot + 2-shuffle butterfly over LQ groups ----
    float p = 0.0f;
#pragma unroll
    for (int j = 0; j < 8; ++j) p = __builtin_fmaf(hv[j], wdv[j], p);
    p += __shfl_xor(p, 16);
    p += __shfl_xor(p, 32);
    p += bdv;                      // every lane of column LC now holds pred(batch LC)
    if (LQ == 0) predbuf[LC * 25 + 0] = p;

    // ---- decode: swap in decode-cell weights ----
    load_weights(Uk_d, Wk_d, b_d, Ahi, Alo, wkfr, bfr, LQ, LC);

    for (int s = 1; s < OUT_STEPS; ++s) {
        lstm_step2(p, Ahi, Alo, wkfr, bfr, h_hi, h_lo, c, hv);
        p = 0.0f;
#pragma unroll
        for (int j = 0; j < 8; ++j) p = __builtin_fmaf(hv[j], wdv[j], p);
        p += __shfl_xor(p, 16);
        p += __shfl_xor(p, 32);
        p += bdv;
        if (LQ == 0) predbuf[LC * 25 + s] = p;
    }

    // ---- coalesced output flush ----
    __syncthreads();
    for (int i = lane; i < 16 * OUT_STEPS; i += 64) {
        int m = i / OUT_STEPS, s = i - m * OUT_STEPS;
        out[(long)mbase * OUT_STEPS + i] = predbuf[m * 25 + s];
    }
}

extern "C" void kernel_launch(void* const* d_in, const int* in_sizes, int n_in,
                              void* d_out, int out_size, void* d_ws, size_t ws_size,
                              hipStream_t stream) {
    const float* inputs = (const float*)d_in[0];
    const float* Wk_w   = (const float*)d_in[1];
    const float* Uk_w   = (const float*)d_in[2];
    const float* b_w    = (const float*)d_in[3];
    const float* Wk_d   = (const float*)d_in[4];
    const float* Uk_d   = (const float*)d_in[5];
    const float* b_d    = (const float*)d_in[6];
    const float* Wd     = (const float*)d_in[7];
    const float* bd     = (const float*)d_in[8];
    float* out = (float*)d_out;

    const int B = in_sizes[0] / TSTEPS;
    const int grid = (B + 15) / 16;   // one wave per 16 batch rows
    lstm_feedback_mfma2<<<grid, 64, 0, stream>>>(
        inputs, Wk_w, Uk_w, b_w, Wk_d, Uk_d, b_d, Wd, bd, out, B);
}